// Round 2
// baseline (727.330 us; speedup 1.0000x reference)
//
#include <hip/hip_runtime.h>

#define N_NODES 100000
#define N_HYPER 20000
#define N_EDGES 1600000
#define LDW 136   // LDS row stride in bf16 elems: 272 B = odd*16B (16B-aligned, bank-decorrelated)

typedef unsigned short u16;
typedef unsigned int u32;
typedef short bf16x8 __attribute__((ext_vector_type(8)));
typedef float f32x4 __attribute__((ext_vector_type(4)));
typedef int i32x4 __attribute__((ext_vector_type(4)));

__device__ __forceinline__ f32x4 mfma16(bf16x8 a, bf16x8 b, f32x4 c) {
    return __builtin_amdgcn_mfma_f32_16x16x32_bf16(a, b, c, 0, 0, 0);
}
__device__ __forceinline__ u16 f2bf(float f) {
    unsigned u = __float_as_uint(f);
    unsigned r = u + 0x7FFFu + ((u >> 16) & 1u);   // RN-even
    return (u16)(r >> 16);
}
__device__ __forceinline__ void bfu(unsigned v, float& f0, float& f1) {
    f0 = __uint_as_float(v << 16);
    f1 = __uint_as_float(v & 0xFFFF0000u);
}

// ------- weight prep (bf16, N-major K-contiguous) + h -> bf16 copy ----------
__global__ __launch_bounds__(256) void k_prep(const float* __restrict__ W1, const float* __restrict__ W2,
                                              const float* __restrict__ W3, const float* __restrict__ W4,
                                              u16* __restrict__ W1t, u16* __restrict__ W2t,
                                              u16* __restrict__ W3t, u16* __restrict__ W4t,
                                              const float* __restrict__ h, u16* __restrict__ h_bf) {
    int i = blockIdx.x * 256 + threadIdx.x;
    if (i < 16384) {
        int k = i & 127, n = i >> 7;
        W1t[n * 128 + k] = f2bf(W1[k * 128 + n]);
        W2t[n * 128 + k] = f2bf(W2[k * 128 + n]);
    }
    if (i < 65536) {
        int k = i & 127, n = i >> 7;          // n < 512
        W3t[n * 128 + k] = f2bf(W3[k * 512 + n]);
        int k4 = i & 511, n4 = i >> 9;        // n4 < 128
        W4t[n4 * 512 + k4] = f2bf(W4[k4 * 128 + n4]);
    }
    if (i < 3276800) {                        // 12.8M elems / 4
        float4 v = ((const float4*)h)[i];
        uint2 st;
        st.x = (u32)f2bf(v.x) | ((u32)f2bf(v.y) << 16);
        st.y = (u32)f2bf(v.z) | ((u32)f2bf(v.w) << 16);
        ((uint2*)h_bf)[i] = st;
    }
}

// ------- CSR build: histogram, XCD-windowed (group g owns 1/8 id range) -----
// nt edge loads: streaming 12.8MB/group must NOT evict the counter window
// from the XCD's L2 (that eviction was the write-amplification source).
__global__ __launch_bounds__(256) void k_hist(const int* __restrict__ src, const int* __restrict__ dst,
                                              int* __restrict__ cnt_node, int* __restrict__ cnt_he) {
    int g = blockIdx.x & 7;
    int node_lo = g * (N_NODES / 8), node_hi = node_lo + N_NODES / 8;
    int he_lo = g * (N_HYPER / 8), he_hi = he_lo + N_HYPER / 8;
    int stride = (gridDim.x >> 3) * 256;
    const i32x4* s4 = (const i32x4*)src;
    const i32x4* d4 = (const i32x4*)dst;
    for (int q = (blockIdx.x >> 3) * 256 + threadIdx.x; q < N_EDGES / 4; q += stride) {
        i32x4 s = __builtin_nontemporal_load(s4 + q);
        i32x4 d = __builtin_nontemporal_load(d4 + q);
        if (s.x >= node_lo && s.x < node_hi) atomicAdd(&cnt_node[s.x], 1);
        if (s.y >= node_lo && s.y < node_hi) atomicAdd(&cnt_node[s.y], 1);
        if (s.z >= node_lo && s.z < node_hi) atomicAdd(&cnt_node[s.z], 1);
        if (s.w >= node_lo && s.w < node_hi) atomicAdd(&cnt_node[s.w], 1);
        if (d.x >= he_lo && d.x < he_hi) atomicAdd(&cnt_he[d.x], 1);
        if (d.y >= he_lo && d.y < he_hi) atomicAdd(&cnt_he[d.y], 1);
        if (d.z >= he_lo && d.z < he_hi) atomicAdd(&cnt_he[d.z], 1);
        if (d.w >= he_lo && d.w < he_hi) atomicAdd(&cnt_he[d.w], 1);
    }
}

// ------- multi-block scan, phase A: per-block sums --------------------------
// blocks 0..24 -> node array (4096 elems each), blocks 25..29 -> he array
__global__ __launch_bounds__(256) void k_scanA(const int* __restrict__ a_node,
                                               const int* __restrict__ a_he,
                                               int* __restrict__ bs) {
    __shared__ int red[256];
    int b = blockIdx.x;
    const int* a; int base, n;
    if (b < 25) { a = a_node; base = b * 4096; n = N_NODES; }
    else        { a = a_he;   base = (b - 25) * 4096; n = N_HYPER; }
    int t = threadIdx.x;
    int lo = base + t * 16;
    int s = 0;
#pragma unroll
    for (int i = 0; i < 16; ++i) {
        int idx = lo + i;
        if (idx < n) s += a[idx];
    }
    red[t] = s;
    __syncthreads();
    for (int off = 128; off > 0; off >>= 1) {
        if (t < off) red[t] += red[t + off];
        __syncthreads();
    }
    if (t == 0) bs[b] = red[0];
}

// ------- phase B: exclusive scan of the 25+5 block sums ---------------------
__global__ void k_scanB(int* __restrict__ bs) {
    int t = threadIdx.x;
    if (t == 0) {
        int run = 0;
        for (int i = 0; i < 25; ++i) { int v = bs[i]; bs[i] = run; run += v; }
    } else if (t == 1) {
        int run = 0;
        for (int i = 25; i < 30; ++i) { int v = bs[i]; bs[i] = run; run += v; }
    }
}

// ------- phase C: block-local scan + apply base; emit offsets + rsqrt(deg) --
__global__ __launch_bounds__(256) void k_scanC(int* __restrict__ a_node, int* __restrict__ a_he,
                                               float* __restrict__ iq_node, float* __restrict__ iq_he,
                                               const int* __restrict__ bs) {
    __shared__ int pre[256];
    int b = blockIdx.x;
    int* a; float* iq; int base, n;
    if (b < 25) { a = a_node; iq = iq_node; base = b * 4096; n = N_NODES; }
    else        { a = a_he;   iq = iq_he;   base = (b - 25) * 4096; n = N_HYPER; }
    int t = threadIdx.x;
    int lo = base + t * 16;
    int loc = 0;
#pragma unroll
    for (int i = 0; i < 16; ++i) { int idx = lo + i; if (idx < n) loc += a[idx]; }
    pre[t] = loc;
    __syncthreads();
    for (int off = 1; off < 256; off <<= 1) {
        int v = (t >= off) ? pre[t - off] : 0;
        __syncthreads();
        pre[t] += v;
        __syncthreads();
    }
    int running = bs[b] + pre[t] - loc;   // global exclusive prefix for this thread
#pragma unroll
    for (int i = 0; i < 16; ++i) {
        int idx = lo + i;
        if (idx < n) {
            int d = a[idx];
            iq[idx] = rsqrtf((float)(d < 1 ? 1 : d));
            a[idx] = running;
            running += d;
        }
    }
}

// ------- CSR build: fill adjacency, XCD-windowed ----------------------------
// nt edge loads keep the ~1.7MB adj+ptr window resident in the XCD's L2 so
// scattered 4B adj writes coalesce into full lines before writeback.
__global__ __launch_bounds__(256) void k_fill(const int* __restrict__ src, const int* __restrict__ dst,
                                              int* __restrict__ ptr_node, int* __restrict__ ptr_he,
                                              int* __restrict__ adj_node, int* __restrict__ adj_he) {
    int g = blockIdx.x & 7;
    int node_lo = g * (N_NODES / 8), node_hi = node_lo + N_NODES / 8;
    int he_lo = g * (N_HYPER / 8), he_hi = he_lo + N_HYPER / 8;
    int stride = (gridDim.x >> 3) * 256;
    const i32x4* s4 = (const i32x4*)src;
    const i32x4* d4 = (const i32x4*)dst;
    for (int q = (blockIdx.x >> 3) * 256 + threadIdx.x; q < N_EDGES / 4; q += stride) {
        i32x4 s = __builtin_nontemporal_load(s4 + q);
        i32x4 d = __builtin_nontemporal_load(d4 + q);
        if (d.x >= he_lo && d.x < he_hi) { int p = atomicAdd(&ptr_he[d.x], 1); adj_he[p] = s.x; }
        if (d.y >= he_lo && d.y < he_hi) { int p = atomicAdd(&ptr_he[d.y], 1); adj_he[p] = s.y; }
        if (d.z >= he_lo && d.z < he_hi) { int p = atomicAdd(&ptr_he[d.z], 1); adj_he[p] = s.z; }
        if (d.w >= he_lo && d.w < he_hi) { int p = atomicAdd(&ptr_he[d.w], 1); adj_he[p] = s.w; }
        if (s.x >= node_lo && s.x < node_hi) { int p = atomicAdd(&ptr_node[s.x], 1); adj_node[p] = d.x; }
        if (s.y >= node_lo && s.y < node_hi) { int p = atomicAdd(&ptr_node[s.y], 1); adj_node[p] = d.y; }
        if (s.z >= node_lo && s.z < node_hi) { int p = atomicAdd(&ptr_node[s.z], 1); adj_node[p] = d.z; }
        if (s.w >= node_lo && s.w < node_hi) { int p = atomicAdd(&ptr_node[s.w], 1); adj_node[p] = d.w; }
    }
}

// ------- gather 1: acc1[d] = sum_{s in adj_he[d]} h_bf[s] * cn[s] -----------
// nt on adj stream (zero reuse) + nt acc1 stores: protect h_bf L2 residency.
__global__ __launch_bounds__(256) void k_gather1(const u16* __restrict__ h_bf,
                                                 const int* __restrict__ adj,
                                                 const int* __restrict__ ptr,
                                                 const float* __restrict__ cn,
                                                 float* __restrict__ acc1) {
    int row = blockIdx.x * 4 + (threadIdx.x >> 6);
    int lane = threadIdx.x & 63;
    int p = lane >> 5, c = lane & 31;
    int start = (row == 0) ? 0 : ptr[row - 1];
    int end = ptr[row];
    const uint2* hp = (const uint2*)h_bf;
    float A0[4] = {0, 0, 0, 0}, A1[4] = {0, 0, 0, 0};
    float f0, f1, f2, f3;
    int j = start;
    for (; j + 3 < end; j += 4) {
        int sA = __builtin_nontemporal_load(adj + j + p);
        int sB = __builtin_nontemporal_load(adj + j + 2 + p);
        float wA = cn[sA], wB = cn[sB];
        uint2 vA = hp[sA * 32 + c];
        uint2 vB = hp[sB * 32 + c];
        bfu(vA.x, f0, f1); bfu(vA.y, f2, f3);
        A0[0] += f0 * wA; A0[1] += f1 * wA; A0[2] += f2 * wA; A0[3] += f3 * wA;
        bfu(vB.x, f0, f1); bfu(vB.y, f2, f3);
        A1[0] += f0 * wB; A1[1] += f1 * wB; A1[2] += f2 * wB; A1[3] += f3 * wB;
    }
    for (; j + 1 < end; j += 2) {
        int sA = __builtin_nontemporal_load(adj + j + p);
        float wA = cn[sA];
        uint2 vA = hp[sA * 32 + c];
        bfu(vA.x, f0, f1); bfu(vA.y, f2, f3);
        A0[0] += f0 * wA; A0[1] += f1 * wA; A0[2] += f2 * wA; A0[3] += f3 * wA;
    }
    if (j < end && p == 0) {
        int sA = __builtin_nontemporal_load(adj + j);
        float wA = cn[sA];
        uint2 vA = hp[sA * 32 + c];
        bfu(vA.x, f0, f1); bfu(vA.y, f2, f3);
        A0[0] += f0 * wA; A0[1] += f1 * wA; A0[2] += f2 * wA; A0[3] += f3 * wA;
    }
    float r0 = A0[0] + A1[0], r1 = A0[1] + A1[1], r2 = A0[2] + A1[2], r3 = A0[3] + A1[3];
    r0 += __shfl_xor(r0, 32, 64);
    r1 += __shfl_xor(r1, 32, 64);
    r2 += __shfl_xor(r2, 32, 64);
    r3 += __shfl_xor(r3, 32, 64);
    if (p == 0) {
        f32x4 o = {r0, r1, r2, r3};
        __builtin_nontemporal_store(o, (f32x4*)acc1 + row * 32 + c);
    }
}

// ------- gather 2: acc2[s] = sum_{d in adj_node[s]} hh2b[d] -----------------
// nt on adj stream + nt acc2 stores (51MB write-allocate would thrash the
// 5.1MB hh2b table we want L2-resident).
__global__ __launch_bounds__(256) void k_gather2(const u16* __restrict__ hh2b,
                                                 const int* __restrict__ adj,
                                                 const int* __restrict__ ptr,
                                                 float* __restrict__ acc2) {
    int row = blockIdx.x * 4 + (threadIdx.x >> 6);
    int lane = threadIdx.x & 63;
    int p = lane >> 5, c = lane & 31;
    int start = (row == 0) ? 0 : ptr[row - 1];
    int end = ptr[row];
    const uint2* hp = (const uint2*)hh2b;
    float A0[4] = {0, 0, 0, 0}, A1[4] = {0, 0, 0, 0};
    float f0, f1, f2, f3;
    int j = start;
    for (; j + 3 < end; j += 4) {
        int dA = __builtin_nontemporal_load(adj + j + p);
        int dB = __builtin_nontemporal_load(adj + j + 2 + p);
        uint2 vA = hp[dA * 32 + c];
        uint2 vB = hp[dB * 32 + c];
        bfu(vA.x, f0, f1); bfu(vA.y, f2, f3);
        A0[0] += f0; A0[1] += f1; A0[2] += f2; A0[3] += f3;
        bfu(vB.x, f0, f1); bfu(vB.y, f2, f3);
        A1[0] += f0; A1[1] += f1; A1[2] += f2; A1[3] += f3;
    }
    for (; j + 1 < end; j += 2) {
        int dA = __builtin_nontemporal_load(adj + j + p);
        uint2 vA = hp[dA * 32 + c];
        bfu(vA.x, f0, f1); bfu(vA.y, f2, f3);
        A0[0] += f0; A0[1] += f1; A0[2] += f2; A0[3] += f3;
    }
    if (j < end && p == 0) {
        int dA = __builtin_nontemporal_load(adj + j);
        uint2 vA = hp[dA * 32 + c];
        bfu(vA.x, f0, f1); bfu(vA.y, f2, f3);
        A0[0] += f0; A0[1] += f1; A0[2] += f2; A0[3] += f3;
    }
    float r0 = A0[0] + A1[0], r1 = A0[1] + A1[1], r2 = A0[2] + A1[2], r3 = A0[3] + A1[3];
    r0 += __shfl_xor(r0, 32, 64);
    r1 += __shfl_xor(r1, 32, 64);
    r2 += __shfl_xor(r2, 32, 64);
    r3 += __shfl_xor(r3, 32, 64);
    if (p == 0) {
        f32x4 o = {r0, r1, r2, r3};
        __builtin_nontemporal_store(o, (f32x4*)acc2 + row * 32 + c);
    }
}

// ------- GEMM1 (MFMA): hh2b = bf16(((acc1*ch) @ W1 + b1) * ch) --------------
__global__ __launch_bounds__(256) void k_gemm1(const float* __restrict__ a, const float* __restrict__ ch,
                                               const u16* __restrict__ W1t,
                                               const float* __restrict__ b1,
                                               u16* __restrict__ hh2b) {
    __shared__ u16 sA[64 * LDW];
    __shared__ u16 sW[128 * LDW];
    int tid = threadIdx.x;
    int r0 = blockIdx.x * 64;
    for (int i = tid; i < 64 * 32; i += 256) {
        int r = i >> 5, c4 = i & 31;
        int row = r0 + r; if (row > N_HYPER - 1) row = N_HYPER - 1;
        float4 v = *(const float4*)(a + row * 128 + c4 * 4);
        float cw = ch[row];
        u16* p = &sA[r * LDW + c4 * 4];
        p[0] = f2bf(v.x * cw); p[1] = f2bf(v.y * cw);
        p[2] = f2bf(v.z * cw); p[3] = f2bf(v.w * cw);
    }
    for (int i = tid; i < 128 * 16; i += 256) {
        int n = i >> 4, c = i & 15;
        *(uint4*)&sW[n * LDW + c * 8] = *(const uint4*)(W1t + n * 128 + c * 8);
    }
    __syncthreads();
    int w = tid >> 6, l15 = tid & 15, quad = (tid & 63) >> 4;
    f32x4 zero = {0.f, 0.f, 0.f, 0.f};
    f32x4 acc[8];
#pragma unroll
    for (int nt = 0; nt < 8; ++nt) acc[nt] = zero;
    int arow = w * 16 + l15;
#pragma unroll
    for (int kt = 0; kt < 4; ++kt) {
        bf16x8 af = *(bf16x8*)&sA[arow * LDW + kt * 32 + quad * 8];
#pragma unroll
        for (int nt = 0; nt < 8; ++nt) {
            bf16x8 bfv = *(bf16x8*)&sW[(nt * 16 + l15) * LDW + kt * 32 + quad * 8];
            acc[nt] = mfma16(af, bfv, acc[nt]);
        }
    }
#pragma unroll
    for (int r = 0; r < 4; ++r) {
        int row = r0 + w * 16 + quad * 4 + r;
        if (row < N_HYPER) {
            float cw = ch[row];
#pragma unroll
            for (int nt = 0; nt < 8; ++nt) {
                int n = nt * 16 + l15;
                hh2b[row * 128 + n] = f2bf((acc[nt][r] + b1[n]) * cw);
            }
        }
    }
}

// --- GEMM2 + residual + LN1 (MFMA, in-place): a := LN(h + (a*cn)@W2 + b2) ---
__global__ __launch_bounds__(256) void k_gemm2_ln(float* a, const float* __restrict__ cn,
                                                  const u16* __restrict__ W2t,
                                                  const float* __restrict__ b2,
                                                  const float* __restrict__ h,
                                                  const float* __restrict__ gamma1,
                                                  const float* __restrict__ beta1) {
    __shared__ u16 sA[64 * LDW];
    __shared__ u16 sW[128 * LDW];
    int tid = threadIdx.x;
    int r0 = blockIdx.x * 64;
    for (int i = tid; i < 64 * 32; i += 256) {
        int r = i >> 5, c4 = i & 31;
        int row = r0 + r; if (row > N_NODES - 1) row = N_NODES - 1;
        float4 v = *(const float4*)(a + row * 128 + c4 * 4);
        float cw = cn[row];
        u16* p = &sA[r * LDW + c4 * 4];
        p[0] = f2bf(v.x * cw); p[1] = f2bf(v.y * cw);
        p[2] = f2bf(v.z * cw); p[3] = f2bf(v.w * cw);
    }
    for (int i = tid; i < 128 * 16; i += 256) {
        int n = i >> 4, c = i & 15;
        *(uint4*)&sW[n * LDW + c * 8] = *(const uint4*)(W2t + n * 128 + c * 8);
    }
    __syncthreads();
    int w = tid >> 6, l15 = tid & 15, quad = (tid & 63) >> 4;
    f32x4 zero = {0.f, 0.f, 0.f, 0.f};
    f32x4 acc[8];
#pragma unroll
    for (int nt = 0; nt < 8; ++nt) acc[nt] = zero;
    int arow = w * 16 + l15;
#pragma unroll
    for (int kt = 0; kt < 4; ++kt) {
        bf16x8 af = *(bf16x8*)&sA[arow * LDW + kt * 32 + quad * 8];
#pragma unroll
        for (int nt = 0; nt < 8; ++nt) {
            bf16x8 bfv = *(bf16x8*)&sW[(nt * 16 + l15) * LDW + kt * 32 + quad * 8];
            acc[nt] = mfma16(af, bfv, acc[nt]);
        }
    }
    float s1[4] = {0, 0, 0, 0}, s2[4] = {0, 0, 0, 0};
#pragma unroll
    for (int r = 0; r < 4; ++r) {
        int row = r0 + w * 16 + quad * 4 + r;
        int rc = row > N_NODES - 1 ? N_NODES - 1 : row;
#pragma unroll
        for (int nt = 0; nt < 8; ++nt) {
            int n = nt * 16 + l15;
            float t = acc[nt][r] + b2[n] + h[rc * 128 + n];
            acc[nt][r] = t;
            s1[r] += t; s2[r] += t * t;
        }
    }
#pragma unroll
    for (int off = 1; off < 16; off <<= 1) {
#pragma unroll
        for (int r = 0; r < 4; ++r) {
            s1[r] += __shfl_xor(s1[r], off, 64);
            s2[r] += __shfl_xor(s2[r], off, 64);
        }
    }
#pragma unroll
    for (int r = 0; r < 4; ++r) {
        int row = r0 + w * 16 + quad * 4 + r;
        if (row < N_NODES) {
            float mu = s1[r] * (1.f / 128.f);
            float var = s2[r] * (1.f / 128.f) - mu * mu;
            float rs = rsqrtf(var + 1e-5f);
#pragma unroll
            for (int nt = 0; nt < 8; ++nt) {
                int n = nt * 16 + l15;
                a[row * 128 + n] = (acc[nt][r] - mu) * rs * gamma1[n] + beta1[n];
            }
        }
    }
}

// ------- FFN + residual + LN2 (MFMA): out = LN(h1 + relu(h1@W3+b3)@W4+b4) ---
__global__ __launch_bounds__(256) void k_ffn_ln(const float* __restrict__ h1,
                                                const u16* __restrict__ W3t,
                                                const float* __restrict__ b3,
                                                const u16* __restrict__ W4t,
                                                const float* __restrict__ b4,
                                                const float* __restrict__ gamma2,
                                                const float* __restrict__ beta2,
                                                float* __restrict__ out) {
    __shared__ u16 sA[64 * LDW];
    __shared__ u16 sW[128 * LDW];
    __shared__ u16 sY[64 * LDW];
    int tid = threadIdx.x;
    int r0 = blockIdx.x * 64;
    for (int i = tid; i < 64 * 32; i += 256) {
        int r = i >> 5, c4 = i & 31;
        int row = r0 + r; if (row > N_NODES - 1) row = N_NODES - 1;
        float4 v = *(const float4*)(h1 + row * 128 + c4 * 4);
        u16* p = &sA[r * LDW + c4 * 4];
        p[0] = f2bf(v.x); p[1] = f2bf(v.y); p[2] = f2bf(v.z); p[3] = f2bf(v.w);
    }
    int w = tid >> 6, l15 = tid & 15, quad = (tid & 63) >> 4;
    int arow = w * 16 + l15;
    f32x4 zero = {0.f, 0.f, 0.f, 0.f};
    f32x4 acc[8];
#pragma unroll
    for (int nt = 0; nt < 8; ++nt) acc[nt] = zero;

    for (int nc = 0; nc < 4; ++nc) {
        __syncthreads();
        for (int i = tid; i < 128 * 16; i += 256) {
            int n = i >> 4, c = i & 15;
            *(uint4*)&sW[n * LDW + c * 8] = *(const uint4*)(W3t + (nc * 128 + n) * 128 + c * 8);
        }
        __syncthreads();
        f32x4 y[8];
#pragma unroll
        for (int nt = 0; nt < 8; ++nt) y[nt] = zero;
#pragma unroll
        for (int kt = 0; kt < 4; ++kt) {
            bf16x8 af = *(bf16x8*)&sA[arow * LDW + kt * 32 + quad * 8];
#pragma unroll
            for (int nt = 0; nt < 8; ++nt) {
                bf16x8 bfv = *(bf16x8*)&sW[(nt * 16 + l15) * LDW + kt * 32 + quad * 8];
                y[nt] = mfma16(af, bfv, y[nt]);
            }
        }
#pragma unroll
        for (int r = 0; r < 4; ++r) {
            int yrow = w * 16 + quad * 4 + r;
#pragma unroll
            for (int nt = 0; nt < 8; ++nt) {
                int n = nt * 16 + l15;
                float vv = y[nt][r] + b3[nc * 128 + n];
                sY[yrow * LDW + n] = f2bf(vv > 0.f ? vv : 0.f);
            }
        }
        __syncthreads();
        for (int i = tid; i < 128 * 16; i += 256) {
            int n = i >> 4, c = i & 15;
            *(uint4*)&sW[n * LDW + c * 8] = *(const uint4*)(W4t + n * 512 + nc * 128 + c * 8);
        }
        __syncthreads();
#pragma unroll
        for (int kt = 0; kt < 4; ++kt) {
            bf16x8 af = *(bf16x8*)&sY[arow * LDW + kt * 32 + quad * 8];
#pragma unroll
            for (int nt = 0; nt < 8; ++nt) {
                bf16x8 bfv = *(bf16x8*)&sW[(nt * 16 + l15) * LDW + kt * 32 + quad * 8];
                acc[nt] = mfma16(af, bfv, acc[nt]);
            }
        }
    }
    float s1[4] = {0, 0, 0, 0}, s2[4] = {0, 0, 0, 0};
#pragma unroll
    for (int r = 0; r < 4; ++r) {
        int row = r0 + w * 16 + quad * 4 + r;
        int rc = row > N_NODES - 1 ? N_NODES - 1 : row;
#pragma unroll
        for (int nt = 0; nt < 8; ++nt) {
            int n = nt * 16 + l15;
            float t = acc[nt][r] + b4[n] + h1[rc * 128 + n];
            acc[nt][r] = t;
            s1[r] += t; s2[r] += t * t;
        }
    }
#pragma unroll
    for (int off = 1; off < 16; off <<= 1) {
#pragma unroll
        for (int r = 0; r < 4; ++r) {
            s1[r] += __shfl_xor(s1[r], off, 64);
            s2[r] += __shfl_xor(s2[r], off, 64);
        }
    }
#pragma unroll
    for (int r = 0; r < 4; ++r) {
        int row = r0 + w * 16 + quad * 4 + r;
        if (row < N_NODES) {
            float mu = s1[r] * (1.f / 128.f);
            float var = s2[r] * (1.f / 128.f) - mu * mu;
            float rs = rsqrtf(var + 1e-5f);
#pragma unroll
            for (int nt = 0; nt < 8; ++nt) {
                int n = nt * 16 + l15;
                out[row * 128 + n] = (acc[nt][r] - mu) * rs * gamma2[n] + beta2[n];
            }
        }
    }
}

extern "C" void kernel_launch(void* const* d_in, const int* in_sizes, int n_in,
                              void* d_out, int out_size, void* d_ws, size_t ws_size,
                              hipStream_t stream) {
    const float* h      = (const float*)d_in[0];
    const int*   src    = (const int*)d_in[1];
    const int*   dst    = (const int*)d_in[2];
    const float* W1     = (const float*)d_in[3];
    const float* b1     = (const float*)d_in[4];
    const float* W2     = (const float*)d_in[5];
    const float* b2     = (const float*)d_in[6];
    const float* W3     = (const float*)d_in[7];
    const float* b3     = (const float*)d_in[8];
    const float* W4     = (const float*)d_in[9];
    const float* b4     = (const float*)d_in[10];
    const float* gamma1 = (const float*)d_in[11];
    const float* beta1  = (const float*)d_in[12];
    const float* gamma2 = (const float*)d_in[13];
    const float* beta2  = (const float*)d_in[14];
    float* out = (float*)d_out;

    // ws layout (bytes), with dead-region aliasing:
    // ptr_node int[100000]     @ 0
    // ptr_he   int[20000]      @ 400000
    // adj_he   int[1.6M]       @ 480000    } hh2b bf16[20000*128] aliases adj_he after gather1
    // adj_node int[1.6M]       @ 6880000
    // cn       f32[100000]     @ 13280000
    // ch       f32[20000]      @ 13680000
    // acc1     f32[20000*128]  @ 13760000  } bs int[30] aliases acc1 during scan phase
    // acc2/h1  f32[100000*128] @ 24000000  } h_bf bf16[100000*128] aliases acc2 until gather2
    // W1t bf16[128*128]        @ 75200000
    // W2t bf16[128*128]        @ 75232768
    // W3t bf16[512*128]        @ 75265536
    // W4t bf16[128*512]        @ 75396608   (end 75527680)
    char* ws = (char*)d_ws;
    int*   ptr_node = (int*)(ws + 0);
    int*   ptr_he   = (int*)(ws + 400000);
    int*   adj_he   = (int*)(ws + 480000);
    int*   adj_node = (int*)(ws + 6880000);
    float* cn       = (float*)(ws + 13280000);
    float* ch       = (float*)(ws + 13680000);
    float* acc1     = (float*)(ws + 13760000);
    float* acc2     = (float*)(ws + 24000000);
    u16*   W1t      = (u16*)(ws + 75200000);
    u16*   W2t      = (u16*)(ws + 75232768);
    u16*   W3t      = (u16*)(ws + 75265536);
    u16*   W4t      = (u16*)(ws + 75396608);
    u16*   h_bf     = (u16*)(ws + 24000000);   // alias acc2 (dead until gather2)
    u16*   hh2b     = (u16*)(ws + 480000);     // alias adj_he (dead after gather1)
    int*   bs       = (int*)(ws + 13760000);   // alias acc1 (dead until gather1)

    hipMemsetAsync(d_ws, 0, 480000, stream);   // zero the two counter arrays only

    k_prep<<<12800, 256, 0, stream>>>(W1, W2, W3, W4, W1t, W2t, W3t, W4t, h, h_bf);
    k_hist<<<2048, 256, 0, stream>>>(src, dst, ptr_node, ptr_he);
    k_scanA<<<30, 256, 0, stream>>>(ptr_node, ptr_he, bs);
    k_scanB<<<1, 64, 0, stream>>>(bs);
    k_scanC<<<30, 256, 0, stream>>>(ptr_node, ptr_he, cn, ch, bs);
    k_fill<<<2048, 256, 0, stream>>>(src, dst, ptr_node, ptr_he, adj_node, adj_he);
    k_gather1<<<5000, 256, 0, stream>>>(h_bf, adj_he, ptr_he, cn, acc1);
    k_gemm1<<<313, 256, 0, stream>>>(acc1, ch, W1t, b1, hh2b);
    k_gather2<<<25000, 256, 0, stream>>>(hh2b, adj_node, ptr_node, acc2);
    k_gemm2_ln<<<1563, 256, 0, stream>>>(acc2, cn, W2t, b2, h, gamma1, beta1);
    k_ffn_ln<<<1563, 256, 0, stream>>>(acc2, W3t, b3, W4t, b4, gamma2, beta2, out);
}